// Round 7
// baseline (430.289 us; speedup 1.0000x reference)
//
#include <hip/hip_runtime.h>
#include <hip/hip_bf16.h>
#include <stdint.h>
#include <stddef.h>

// B=2, S=2048, E=1024, H=16, DH=64. fp32 I/O, int32 mask, bf16 internal.
#define SB 2
#define SS 2048
#define SE 1024
#define SH 16
#define SD 64

typedef __attribute__((ext_vector_type(8))) short bf16x8;  // 8 bf16, 4 VGPRs
typedef __attribute__((ext_vector_type(4))) float f32x4;

__device__ __forceinline__ short f2bf(float f) {
    union { float f; uint32_t u; } v; v.f = f;
    uint32_t u = v.u;
    uint32_t r = (u + 0x7fffu + ((u >> 16) & 1u)) >> 16;  // RNE
    return (short)(uint16_t)r;
}

// masked RNE f32->bf16 pair pack: bit0 -> a, bit1 -> b (0 if masked out)
__device__ __forceinline__ uint32_t pkmask(float a, float b, uint32_t bits) {
    union { float f; uint32_t u; } ua, ub;
    ua.f = a; ub.f = b;
    uint32_t ra = (bits & 1u) ? (ua.u + 0x7fffu + ((ua.u >> 16) & 1u)) : 0u;
    uint32_t rb = (bits & 2u) ? (ub.u + 0x7fffu + ((ub.u >> 16) & 1u)) : 0u;
    return (rb & 0xffff0000u) | (ra >> 16);
}

// async 16B global->LDS (wave-uniform LDS base + lane*16 semantics)
__device__ __forceinline__ void gld16(const short* g, short* l) {
    __builtin_amdgcn_global_load_lds(
        (const __attribute__((address_space(1))) unsigned int*)g,
        (__attribute__((address_space(3))) unsigned int*)l, 16, 0, 0);
}

// ---------------------------------------------------------------------------
// Bulk fp32 -> bf16. Grid (2048, 7): jobs 0-2 q,k,v (2048 blk), 3-6 W* (512).
// ---------------------------------------------------------------------------
struct CvtArgs {
    const float* src[7];
    short* dst[7];
    int nblk[7];
};

__global__ __launch_bounds__(256) void cvt_bf16(CvtArgs a) {
    const int j = blockIdx.y;
    if (blockIdx.x >= a.nblk[j]) return;
    const size_t i = ((size_t)blockIdx.x * 256 + threadIdx.x) * 8;
    const float* s = a.src[j] + i;
    f32x4 f0 = *(const f32x4*)s;
    f32x4 f1 = *(const f32x4*)(s + 4);
    bf16x8 o;
    o[0] = f2bf(f0[0]); o[1] = f2bf(f0[1]); o[2] = f2bf(f0[2]); o[3] = f2bf(f0[3]);
    o[4] = f2bf(f1[0]); o[5] = f2bf(f1[1]); o[6] = f2bf(f1[2]); o[7] = f2bf(f1[3]);
    *(bf16x8*)(a.dst[j] + i) = o;
}

// ---------------------------------------------------------------------------
// Pack mask [B,1,S,S] int32 -> 1 bit, TRANSPOSED layout:
//   mp[b*65536 + kw*2048 + q], kw = k/64, bit j = mask[b][q][kw*64+j]
// ---------------------------------------------------------------------------
__global__ __launch_bounds__(256) void pack_mask(const int* __restrict__ m,
                                                 unsigned long long* __restrict__ mp) {
    const int lane = threadIdx.x & 63;
    int wv = (blockIdx.x * 256 + threadIdx.x) >> 6;
    const int NW = SB * SS * (SS / 64);  // 131072 words
    const int stride = (gridDim.x * 256) >> 6;
    for (int wd = wv; wd < NW; wd += stride) {
        int v = m[(size_t)wd * 64 + lane];
        unsigned long long bb = __ballot(v != 0);
        if (lane == 0) {
            int b = wd >> 16;
            int q = (wd >> 5) & 2047;
            int kw = wd & 31;
            mp[((size_t)b << 16) + kw * 2048 + q] = bb;
        }
    }
}

struct GemmJob {
    const short* A; const short* W; const float* bias; void* C;
    int mode;      // 0: [M,1024] row-major; 1: [B,H,S,DH]; 3: Vt=[B,H,DH,S] swapped
    float scale;
};

// ---------------------------------------------------------------------------
// bf16 GEMM, 64x128 tile, BK=64, gld16 staging (m97 recipe), 4 waves of 32x64.
// z<2: m0 = y*64 over M=4096, n0 = x*128 over N=1024 (modes 0/1).
// z==2 (Vt): A=Wv (M=1024), W=value (N=4096); flat id remap; mode 3 writes
//   C[b, m(=h*64+d), s] with bias[m] — contiguous-in-s stores (no scatter).
// ---------------------------------------------------------------------------
template <bool OUTF32>
__global__ __launch_bounds__(256, 4) void gemm64(GemmJob j0, GemmJob j1, GemmJob j2) {
    GemmJob j = (blockIdx.z == 0) ? j0 : (blockIdx.z == 1) ? j1 : j2;
    __shared__ short As[64 * 64];    // 8 KB
    __shared__ short Bs[128 * 64];   // 16 KB

    int m0, n0;
    if (blockIdx.z == 2) {
        int id = blockIdx.y * 8 + blockIdx.x;   // 0..511
        m0 = (id >> 5) * 64;                    // 16 tiles over 1024
        n0 = (id & 31) * 128;                   // 32 tiles over 4096
    } else {
        m0 = blockIdx.y * 64;
        n0 = blockIdx.x * 128;
    }

    const int tid = threadIdx.x;
    const int lane = tid & 63;
    const int w = tid >> 6;
    const int wm = (w >> 1) * 32;
    const int wn = (w & 1) * 64;
    const int quad = lane >> 4;
    const int l16 = lane & 15;

    f32x4 acc[2][4] = {};

    for (int k0 = 0; k0 < 1024; k0 += 64) {
#pragma unroll
        for (int g = 0; g < 2; ++g) {
            int ch = g * 256 + w * 64 + lane;
            gld16(j.A + (size_t)(m0 + (ch >> 3)) * 1024 + k0 + (ch & 7) * 8,
                  &As[(g * 256 + w * 64) * 8]);
        }
#pragma unroll
        for (int g = 0; g < 4; ++g) {
            int ch = g * 256 + w * 64 + lane;
            gld16(j.W + (size_t)(n0 + (ch >> 3)) * 1024 + k0 + (ch & 7) * 8,
                  &Bs[(g * 256 + w * 64) * 8]);
        }
        __syncthreads();
#pragma unroll
        for (int ks = 0; ks < 2; ++ks) {
            bf16x8 af[2], bfr[4];
#pragma unroll
            for (int mi = 0; mi < 2; ++mi)
                af[mi] = *(const bf16x8*)&As[(wm + mi * 16 + l16) * 64 + ks * 32 + quad * 8];
#pragma unroll
            for (int ni = 0; ni < 4; ++ni)
                bfr[ni] = *(const bf16x8*)&Bs[(wn + ni * 16 + l16) * 64 + ks * 32 + quad * 8];
#pragma unroll
            for (int mi = 0; mi < 2; ++mi)
#pragma unroll
                for (int ni = 0; ni < 4; ++ni)
                    acc[mi][ni] = __builtin_amdgcn_mfma_f32_16x16x32_bf16(
                        af[mi], bfr[ni], acc[mi][ni], 0, 0, 0);
        }
        __syncthreads();
    }

    // Epilogue. C/D: col(n)=l16, row(m)=quad*4+reg.
#pragma unroll
    for (int mi = 0; mi < 2; ++mi) {
#pragma unroll
        for (int ni = 0; ni < 4; ++ni) {
            int n = n0 + wn + ni * 16 + l16;
            float bvn = (j.mode == 3) ? 0.0f : j.bias[n];
#pragma unroll
            for (int r = 0; r < 4; ++r) {
                int m = m0 + wm + mi * 16 + quad * 4 + r;
                float bias = (j.mode == 3) ? j.bias[m] : bvn;
                float v = (acc[mi][ni][r] + bias) * j.scale;
                if (OUTF32) {
                    ((float*)j.C)[(size_t)m * 1024 + n] = v;
                } else {
                    short o = f2bf(v);
                    short* C = (short*)j.C;
                    if (j.mode == 0) {
                        C[(size_t)m * 1024 + n] = o;
                    } else if (j.mode == 1) {
                        int b = m >> 11, s = m & 2047;
                        int hh = n >> 6, d = n & 63;
                        C[(((size_t)(b * SH + hh) * SS) + s) * SD + d] = o;
                    } else {  // mode 3: Vt[b][m(=hd)][s], n = b*2048+s
                        C[((size_t)(n >> 11) << 21) + (size_t)m * 2048 + (n & 2047)] = o;
                    }
                }
            }
        }
    }
}

// ---------------------------------------------------------------------------
// attn3: no-softmax attention, k-split waves.
// Block = (64 q, bh); each wave handles ALL 64 q and a 32-k quarter of each
// 128-k tile. Phase 1: Sc^T = K.Q^T (C/D layout == phase-2 A-frag layout, up
// to a k-permutation shared with the V B-frags). Mask from transposed packed
// bits, applied in registers (1e-9 -> 0: below bf16 ULP of the output).
// K [128][72] and V [64][136] LDS-staged padded; epilogue: 2-round fp32
// cross-wave reduction of the 4 k-partial O accumulators through LDS.
// ---------------------------------------------------------------------------
__global__ __launch_bounds__(256, 3) void attn3(
    const short* __restrict__ Q,   // [B,H,S,DH] bf16
    const short* __restrict__ Kk,  // [B,H,S,DH] bf16
    const short* __restrict__ Vt,  // [B,H,DH,S] bf16
    const unsigned long long* __restrict__ MpT,  // [B][32 kw][2048 q]
    short* __restrict__ O) {       // merged heads [B,S,E] bf16
    __shared__ __align__(16) char pool[35840];
    short* Ks = (short*)pool;              // [128][72] = 18432 B
    short* Vs = (short*)(pool + 18432);    // [64][136] = 17408 B
    float* R0 = (float*)pool;              // reduction regions (reused)
    float* R1 = (float*)(pool + 17408);

    const int qt = blockIdx.x;
    const int bh = blockIdx.y;
    const int b = bh >> 4;
    const int h = bh & 15;
    const int q0 = qt * 64;

    const short* qbase = Q + (size_t)bh * SS * SD;
    const short* kbase = Kk + (size_t)bh * SS * SD;
    const short* vbase = Vt + (size_t)bh * SD * SS;
    const unsigned long long* mTb = MpT + ((size_t)b << 16);

    const int tid = threadIdx.x;
    const int lane = tid & 63;
    const int w = tid >> 6;
    const int quad = lane >> 4;
    const int l16 = lane & 15;
    const int wk = w * 32;          // this wave's k-quarter within the 128-tile
    const int kk = (w & 1) * 32;    // bit offset within the 64-bit mask word
    const int kwofs = w >> 1;       // mask word offset

    // Persistent Q B-frags: all 64 q, d contracted in two halves
    bf16x8 qf[4][2];
#pragma unroll
    for (int qg = 0; qg < 4; ++qg)
#pragma unroll
        for (int hh = 0; hh < 2; ++hh)
            qf[qg][hh] = *(const bf16x8*)(qbase +
                (size_t)(q0 + qg * 16 + l16) * SD + hh * 32 + quad * 8);

    f32x4 oacc[4][4] = {};  // [qg][di], partial over this wave's k

    // K/V staging: 1024 chunks each, 4 per thread
    bf16x8 kpf[4], vpf[4];
    auto loadKV = [&](int k0) {
#pragma unroll
        for (int r = 0; r < 4; ++r) {
            int ch = tid + r * 256;
            kpf[r] = *(const bf16x8*)(kbase + (size_t)(k0 + (ch >> 3)) * SD + (ch & 7) * 8);
            vpf[r] = *(const bf16x8*)(vbase + (size_t)(ch >> 4) * SS + k0 + (ch & 15) * 8);
        }
    };
    auto storeKV = [&]() {
#pragma unroll
        for (int r = 0; r < 4; ++r) {
            int ch = tid + r * 256;
            *(bf16x8*)&Ks[(ch >> 3) * 72 + (ch & 7) * 8] = kpf[r];
            *(bf16x8*)&Vs[(ch >> 4) * 136 + (ch & 15) * 8] = vpf[r];
        }
    };

    loadKV(0);
    for (int k0 = 0; k0 < SS; k0 += 128) {
        __syncthreads();   // previous iteration's LDS reads complete
        storeKV();
        __syncthreads();   // tiles visible
        if (k0 + 128 < SS) loadKV(k0 + 128);  // prefetch overlaps compute

        // mask words for my k-quarter, all 4 q-groups
        unsigned long long mw[4];
#pragma unroll
        for (int qg = 0; qg < 4; ++qg)
            mw[qg] = mTb[(size_t)(((k0 >> 6) + kwofs) * 2048 + q0 + qg * 16 + l16)];

        // K A-frags for my two 16-k subtiles (shared across q-groups)
        bf16x8 aK[4];  // [s*2+hh]
#pragma unroll
        for (int s = 0; s < 2; ++s)
#pragma unroll
            for (int hh = 0; hh < 2; ++hh)
                aK[s * 2 + hh] = *(const bf16x8*)&Ks[(wk + s * 16 + l16) * 72 +
                                                     hh * 32 + quad * 8];

        // Phase 1 + mask fold: Sc^T -> phase-2 A-frags (register-resident)
        bf16x8 scf[4];
#pragma unroll
        for (int qg = 0; qg < 4; ++qg) {
            f32x4 sA = {}, sB = {};
            sA = __builtin_amdgcn_mfma_f32_16x16x32_bf16(aK[0], qf[qg][0], sA, 0, 0, 0);
            sA = __builtin_amdgcn_mfma_f32_16x16x32_bf16(aK[1], qf[qg][1], sA, 0, 0, 0);
            sB = __builtin_amdgcn_mfma_f32_16x16x32_bf16(aK[2], qf[qg][0], sB, 0, 0, 0);
            sB = __builtin_amdgcn_mfma_f32_16x16x32_bf16(aK[3], qf[qg][1], sB, 0, 0, 0);
            uint32_t sh0 = (uint32_t)(mw[qg] >> (kk + quad * 4));
            uint32_t sh1 = (uint32_t)(mw[qg] >> (kk + 16 + quad * 4));
            union { uint32_t d[4]; bf16x8 v; } sc;
            sc.d[0] = pkmask(sA[0], sA[1], sh0);
            sc.d[1] = pkmask(sA[2], sA[3], sh0 >> 2);
            sc.d[2] = pkmask(sB[0], sB[1], sh1);
            sc.d[3] = pkmask(sB[2], sB[3], sh1 >> 2);
            scf[qg] = sc.v;
        }

        // Phase 2: O += Sc.V over my 32 k (V B-frags shared across q-groups)
#pragma unroll
        for (int di = 0; di < 4; ++di) {
            union { uint32_t d[4]; bf16x8 v; } vb;
            const uint32_t* vlo = (const uint32_t*)&Vs[(di * 16 + l16) * 136 + wk + quad * 4];
            const uint32_t* vhi = (const uint32_t*)&Vs[(di * 16 + l16) * 136 + wk + 16 + quad * 4];
            vb.d[0] = vlo[0]; vb.d[1] = vlo[1];
            vb.d[2] = vhi[0]; vb.d[3] = vhi[1];
#pragma unroll
            for (int qg = 0; qg < 4; ++qg)
                oacc[qg][di] = __builtin_amdgcn_mfma_f32_16x16x32_bf16(
                    scf[qg], vb.v, oacc[qg][di], 0, 0, 0);
        }
    }
    __syncthreads();  // loop LDS reads done; pool free for reduction

    // Cross-wave reduction: slot = lane*68 dwords (+17 pad), frag idx*4
    auto writeR = [&](float* R) {
#pragma unroll
        for (int qg = 0; qg < 4; ++qg)
#pragma unroll
            for (int di = 0; di < 4; ++di)
                *(f32x4*)(R + (size_t)lane * 68 + (qg * 4 + di) * 4) = oacc[qg][di];
    };
    auto addR = [&](const float* R) {
#pragma unroll
        for (int qg = 0; qg < 4; ++qg)
#pragma unroll
            for (int di = 0; di < 4; ++di)
                oacc[qg][di] += *(const f32x4*)(R + (size_t)lane * 68 + (qg * 4 + di) * 4);
    };

    if (w == 1) writeR(R0);
    if (w == 3) writeR(R1);
    __syncthreads();
    if (w == 0) addR(R0);
    if (w == 2) addR(R1);
    __syncthreads();
    if (w == 2) writeR(R0);
    __syncthreads();
    if (w == 0) {
        addR(R0);
        // write merged-head O [B,S,E]
#pragma unroll
        for (int qg = 0; qg < 4; ++qg)
#pragma unroll
            for (int di = 0; di < 4; ++di) {
                int d = di * 16 + l16;
#pragma unroll
                for (int r = 0; r < 4; ++r) {
                    int qg_ = q0 + qg * 16 + quad * 4 + r;
                    O[((size_t)b * SS + qg_) * SE + h * SD + d] = f2bf(oacc[qg][di][r]);
                }
            }
    }
}

// ---------------------------------------------------------------------------
extern "C" void kernel_launch(void* const* d_in, const int* in_sizes, int n_in,
                              void* d_out, int out_size, void* d_ws,
                              size_t ws_size, hipStream_t stream) {
    const float* query = (const float*)d_in[0];
    const float* key   = (const float*)d_in[1];
    const float* value = (const float*)d_in[2];
    const int*   mask  = (const int*)d_in[3];
    float* out = (float*)d_out;

    // Buffer plan (zero d_ws; harness restores inputs before every launch):
    //  d_out [0,1M):  packed mask MpT (dead before O-proj writes d_out)
    //  mask buffer d_in[3] (33.5 MB) -> bf16 scratch after pack:
    //    [0,8M) qbf | [8,16) kbf | [16,24) vbf | [24,32) Wq|Wk|Wv|Wo
    //  d_in[0]: Qb [0,8M) | Om [8M,16M);  d_in[1]: Kb;  d_in[2]: Vtb
    const size_t NEL = (size_t)SB * SS * SE;  // 4,194,304
    unsigned long long* Mp = (unsigned long long*)d_out;
    short* mb   = (short*)d_in[3];
    short* qbf  = mb;
    short* kbf  = mb + NEL;
    short* vbf  = mb + 2 * NEL;
    short* Wqb  = mb + 3 * NEL;
    short* Wkb  = Wqb + SE * SE;
    short* Wvb  = Wkb + SE * SE;
    short* Wob  = Wvb + SE * SE;
    short* Qb   = (short*)d_in[0];
    short* Om   = (short*)d_in[0] + NEL;
    short* Kb   = (short*)d_in[1];
    short* Vtb  = (short*)d_in[2];

    dim3 tblk(256);

    // 1) pack mask (transposed bit layout) -> d_out  [must precede cvt!]
    pack_mask<<<dim3(1024), tblk, 0, stream>>>(mask, Mp);

    // 2) fp32 -> bf16 for q,k,v,W* into the dead mask buffer
    CvtArgs ca;
    ca.src[0] = query; ca.dst[0] = qbf; ca.nblk[0] = 2048;
    ca.src[1] = key;   ca.dst[1] = kbf; ca.nblk[1] = 2048;
    ca.src[2] = value; ca.dst[2] = vbf; ca.nblk[2] = 2048;
    ca.src[3] = (const float*)d_in[4];  ca.dst[3] = Wqb; ca.nblk[3] = 512;
    ca.src[4] = (const float*)d_in[6];  ca.dst[4] = Wkb; ca.nblk[4] = 512;
    ca.src[5] = (const float*)d_in[8];  ca.dst[5] = Wvb; ca.nblk[5] = 512;
    ca.src[6] = (const float*)d_in[10]; ca.dst[6] = Wob; ca.nblk[6] = 512;
    cvt_bf16<<<dim3(2048, 7), tblk, 0, stream>>>(ca);

    // 3) fused Q,K,Vt projections (1/8 folded into Q; Vt = Wv.value^T swapped)
    GemmJob jq{qbf, Wqb, (const float*)d_in[5], Qb,  1, 0.125f};
    GemmJob jk{kbf, Wkb, (const float*)d_in[7], Kb,  1, 1.0f};
    GemmJob jv{Wvb, vbf, (const float*)d_in[9], Vtb, 3, 1.0f};
    gemm64<false><<<dim3(8, 64, 3), tblk, 0, stream>>>(jq, jk, jv);

    // 4) attention (register-resident scores, k-split waves)
    attn3<<<dim3(SS / 64, SB * SH), tblk, 0, stream>>>(Qb, Kb, Vtb, Mp, Om);

    // 5) output projection (fp32 out; overwrites Mp region - dead)
    GemmJob jo{Om, Wob, (const float*)d_in[11], out, 0, 1.0f};
    gemm64<true><<<dim3(8, 64, 1), tblk, 0, stream>>>(jo, jo, jo);
}

// Round 8
// 347.356 us; speedup vs baseline: 1.2388x; 1.2388x over previous
//
#include <hip/hip_runtime.h>
#include <hip/hip_bf16.h>
#include <stdint.h>
#include <stddef.h>

// B=2, S=2048, E=1024, H=16, DH=64. fp32 I/O, int32 mask, bf16 internal.
#define SB 2
#define SS 2048
#define SE 1024
#define SH 16
#define SD 64

typedef __attribute__((ext_vector_type(8))) short bf16x8;  // 8 bf16, 4 VGPRs
typedef __attribute__((ext_vector_type(4))) float f32x4;

__device__ __forceinline__ short f2bf(float f) {
    union { float f; uint32_t u; } v; v.f = f;
    uint32_t u = v.u;
    uint32_t r = (u + 0x7fffu + ((u >> 16) & 1u)) >> 16;  // RNE
    return (short)(uint16_t)r;
}

// masked RNE f32->bf16 pair pack: bit0 -> a, bit1 -> b (0 if masked out)
__device__ __forceinline__ uint32_t pkmask(float a, float b, uint32_t bits) {
    union { float f; uint32_t u; } ua, ub;
    ua.f = a; ub.f = b;
    uint32_t ra = (bits & 1u) ? (ua.u + 0x7fffu + ((ua.u >> 16) & 1u)) : 0u;
    uint32_t rb = (bits & 2u) ? (ub.u + 0x7fffu + ((ub.u >> 16) & 1u)) : 0u;
    return (rb & 0xffff0000u) | (ra >> 16);
}

// async 16B global->LDS (wave-uniform LDS base + lane*16 semantics)
__device__ __forceinline__ void gld16(const short* g, short* l) {
    __builtin_amdgcn_global_load_lds(
        (const __attribute__((address_space(1))) unsigned int*)g,
        (__attribute__((address_space(3))) unsigned int*)l, 16, 0, 0);
}

// ---------------------------------------------------------------------------
// Bulk fp32 -> bf16, uniform grid-stride over 8192 wave-units of 2048 elts.
// Units: q,k,v = 3*2048; Wq,Wk,Wv,Wo = 4*512. Grid 2048 blocks x 256.
// ---------------------------------------------------------------------------
struct CvtArgs {
    const float* src[7];
    short* dst[7];
};

__global__ __launch_bounds__(256) void cvt_bf16(CvtArgs a) {
    const int wave = (blockIdx.x * 256 + threadIdx.x) >> 6;  // 0..8191
    const int lane = threadIdx.x & 63;
    int seg, local;
    if (wave < 6144) { seg = wave >> 11; local = wave & 2047; }
    else { int t = wave - 6144; seg = 3 + (t >> 9); local = t & 511; }
    const float* s = a.src[seg] + (size_t)local * 2048;
    short* d = a.dst[seg] + (size_t)local * 2048;
#pragma unroll
    for (int i = 0; i < 4; ++i) {
        size_t off = (size_t)(i * 64 + lane) * 8;
        f32x4 f0 = *(const f32x4*)(s + off);
        f32x4 f1 = *(const f32x4*)(s + off + 4);
        bf16x8 o;
        o[0] = f2bf(f0[0]); o[1] = f2bf(f0[1]); o[2] = f2bf(f0[2]); o[3] = f2bf(f0[3]);
        o[4] = f2bf(f1[0]); o[5] = f2bf(f1[1]); o[6] = f2bf(f1[2]); o[7] = f2bf(f1[3]);
        *(bf16x8*)(d + off) = o;
    }
}

// ---------------------------------------------------------------------------
// Pack mask [B,1,S,S] int32 -> 1 bit, TRANSPOSED layout:
//   mp[b*65536 + kw*2048 + q], kw = k/64, bit j = mask[b][q][kw*64+j]
// Grid 2048 blocks x 256 = 8192 waves x 16 words.
// ---------------------------------------------------------------------------
__global__ __launch_bounds__(256) void pack_mask(const int* __restrict__ m,
                                                 unsigned long long* __restrict__ mp) {
    const int lane = threadIdx.x & 63;
    const int wv = (blockIdx.x * 256 + threadIdx.x) >> 6;  // 0..8191
#pragma unroll
    for (int i = 0; i < 16; ++i) {
        int wd = wv * 16 + i;
        int v = m[(size_t)wd * 64 + lane];
        unsigned long long bb = __ballot(v != 0);
        if (lane == 0) {
            int b = wd >> 16;
            int q = (wd >> 5) & 2047;
            int kw = wd & 31;
            mp[((size_t)b << 16) + kw * 2048 + q] = bb;
        }
    }
}

struct GemmJob {
    const short* A; const short* W; const float* bias; void* C;
    int mode;      // 0: [M,1024] row-major; 1: [B,H,S,DH]; 3: Vt=[B,H,DH,S] swapped
    float scale;
};

// ---------------------------------------------------------------------------
// bf16 GEMM, 64x128 tile, BK=64, gld16 staging, 4 waves of 32x64.
// z<2: m0 = y*64 over M=4096, n0 = x*128 over N=1024 (modes 0/1).
// z==2 (Vt): A=Wv (M=1024), W=value (N=4096); mode 3 writes C[b, h*64+d, s].
// ---------------------------------------------------------------------------
template <bool OUTF32>
__global__ __launch_bounds__(256, 4) void gemm64(GemmJob j0, GemmJob j1, GemmJob j2) {
    GemmJob j = (blockIdx.z == 0) ? j0 : (blockIdx.z == 1) ? j1 : j2;
    __shared__ short As[64 * 64];    // 8 KB
    __shared__ short Bs[128 * 64];   // 16 KB

    int m0, n0;
    if (blockIdx.z == 2) {
        int id = blockIdx.y * 8 + blockIdx.x;   // 0..511
        m0 = (id >> 5) * 64;                    // 16 tiles over 1024
        n0 = (id & 31) * 128;                   // 32 tiles over 4096
    } else {
        m0 = blockIdx.y * 64;
        n0 = blockIdx.x * 128;
    }

    const int tid = threadIdx.x;
    const int lane = tid & 63;
    const int w = tid >> 6;
    const int wm = (w >> 1) * 32;
    const int wn = (w & 1) * 64;
    const int quad = lane >> 4;
    const int l16 = lane & 15;

    f32x4 acc[2][4] = {};

    for (int k0 = 0; k0 < 1024; k0 += 64) {
#pragma unroll
        for (int g = 0; g < 2; ++g) {
            int ch = g * 256 + w * 64 + lane;
            gld16(j.A + (size_t)(m0 + (ch >> 3)) * 1024 + k0 + (ch & 7) * 8,
                  &As[(g * 256 + w * 64) * 8]);
        }
#pragma unroll
        for (int g = 0; g < 4; ++g) {
            int ch = g * 256 + w * 64 + lane;
            gld16(j.W + (size_t)(n0 + (ch >> 3)) * 1024 + k0 + (ch & 7) * 8,
                  &Bs[(g * 256 + w * 64) * 8]);
        }
        __syncthreads();
#pragma unroll
        for (int ks = 0; ks < 2; ++ks) {
            bf16x8 af[2], bfr[4];
#pragma unroll
            for (int mi = 0; mi < 2; ++mi)
                af[mi] = *(const bf16x8*)&As[(wm + mi * 16 + l16) * 64 + ks * 32 + quad * 8];
#pragma unroll
            for (int ni = 0; ni < 4; ++ni)
                bfr[ni] = *(const bf16x8*)&Bs[(wn + ni * 16 + l16) * 64 + ks * 32 + quad * 8];
#pragma unroll
            for (int mi = 0; mi < 2; ++mi)
#pragma unroll
                for (int ni = 0; ni < 4; ++ni)
                    acc[mi][ni] = __builtin_amdgcn_mfma_f32_16x16x32_bf16(
                        af[mi], bfr[ni], acc[mi][ni], 0, 0, 0);
        }
        __syncthreads();
    }

    // Epilogue. C/D: col(n)=l16, row(m)=quad*4+reg.
#pragma unroll
    for (int mi = 0; mi < 2; ++mi) {
#pragma unroll
        for (int ni = 0; ni < 4; ++ni) {
            int n = n0 + wn + ni * 16 + l16;
            float bvn = (j.mode == 3) ? 0.0f : j.bias[n];
#pragma unroll
            for (int r = 0; r < 4; ++r) {
                int m = m0 + wm + mi * 16 + quad * 4 + r;
                float bias = (j.mode == 3) ? j.bias[m] : bvn;
                float v = (acc[mi][ni][r] + bias) * j.scale;
                if (OUTF32) {
                    ((float*)j.C)[(size_t)m * 1024 + n] = v;
                } else {
                    short o = f2bf(v);
                    short* C = (short*)j.C;
                    if (j.mode == 0) {
                        C[(size_t)m * 1024 + n] = o;
                    } else if (j.mode == 1) {
                        int b = m >> 11, s = m & 2047;
                        int hh = n >> 6, d = n & 63;
                        C[(((size_t)(b * SH + hh) * SS) + s) * SD + d] = o;
                    } else {  // mode 3: Vt[b][m(=hd)][s], n = b*2048+s
                        C[((size_t)(n >> 11) << 21) + (size_t)m * 2048 + (n & 2047)] = o;
                    }
                }
            }
        }
    }
}

// ---------------------------------------------------------------------------
// attn4: no-softmax attention, k-split waves, ZERO LDS in the main loop.
// Block = (64 q, bh); wave w handles ALL 64 q and k-slices (iter*4+w)*32.
// All K/V/Q/mask reads go straight from global (L1/L2; k-split => zero
// intra-block redundancy, cross-q-tile reuse served by L2).
// Phase 1: Sc^T = K.Q^T (C/D layout == phase-2 A-frag layout up to a shared
// k-permutation). Mask applied in registers (1e-9 -> 0, below output ULP).
// Epilogue: one-barrier cross-wave reduction via LDS (stride-20 slots).
// Register budget fits 256-VGPR cap: oacc 64 + qf 32 + transients ~60.
// ---------------------------------------------------------------------------
__global__ __launch_bounds__(256, 2) void attn4(
    const short* __restrict__ Q,   // [B,H,S,DH] bf16
    const short* __restrict__ Kk,  // [B,H,S,DH] bf16
    const short* __restrict__ Vt,  // [B,H,DH,S] bf16
    const unsigned long long* __restrict__ MpT,  // [B][32 kw][2048 q]
    short* __restrict__ O) {       // merged heads [B,S,E] bf16
    __shared__ float Rs[12 * 1280];  // 60 KB reduction slots (epilogue only)

    const int qt = blockIdx.x;
    const int bh = blockIdx.y;
    const int b = bh >> 4;
    const int h = bh & 15;
    const int q0 = qt * 64;

    const short* qbase = Q + (size_t)bh * SS * SD;
    const short* kbase = Kk + (size_t)bh * SS * SD;
    const short* vbase = Vt + (size_t)bh * SD * SS;
    const unsigned long long* mTb = MpT + ((size_t)b << 16);

    const int tid = threadIdx.x;
    const int lane = tid & 63;
    const int w = tid >> 6;
    const int quad = lane >> 4;
    const int l16 = lane & 15;
    const int mbit = (w & 1) * 32;   // bit offset of this wave's 32-k in the 64-b word

    // Persistent Q B-frags: all 64 q (4 groups of 16), d in two halves
    bf16x8 qf[4][2];
#pragma unroll
    for (int qg = 0; qg < 4; ++qg)
#pragma unroll
        for (int hh = 0; hh < 2; ++hh)
            qf[qg][hh] = *(const bf16x8*)(qbase +
                (size_t)(q0 + qg * 16 + l16) * SD + hh * 32 + quad * 8);

    f32x4 oacc[4][4] = {};  // [qg][di], partial over this wave's k-slices

    for (int it = 0; it < 16; ++it) {
        const int ks0 = (it * 4 + w) * 32;       // this wave's 32-k slice
        const int kw = it * 2 + (w >> 1);        // packed-mask word column

        // K A-frags: two 16-k subtiles x two d-halves (16B global loads)
        bf16x8 aK[4];
#pragma unroll
        for (int s = 0; s < 2; ++s)
#pragma unroll
            for (int hh = 0; hh < 2; ++hh)
                aK[s * 2 + hh] = *(const bf16x8*)(kbase +
                    (size_t)(ks0 + s * 16 + l16) * SD + hh * 32 + quad * 8);

        // mask words for all 4 q-groups
        unsigned long long mw[4];
#pragma unroll
        for (int qg = 0; qg < 4; ++qg)
            mw[qg] = mTb[(size_t)kw * 2048 + q0 + qg * 16 + l16];

        // Phase 1 + mask fold: Sc^T -> phase-2 A-frags (registers only)
        bf16x8 scf[4];
#pragma unroll
        for (int qg = 0; qg < 4; ++qg) {
            f32x4 sA = {}, sB = {};
            sA = __builtin_amdgcn_mfma_f32_16x16x32_bf16(aK[0], qf[qg][0], sA, 0, 0, 0);
            sA = __builtin_amdgcn_mfma_f32_16x16x32_bf16(aK[1], qf[qg][1], sA, 0, 0, 0);
            sB = __builtin_amdgcn_mfma_f32_16x16x32_bf16(aK[2], qf[qg][0], sB, 0, 0, 0);
            sB = __builtin_amdgcn_mfma_f32_16x16x32_bf16(aK[3], qf[qg][1], sB, 0, 0, 0);
            uint32_t sh0 = (uint32_t)(mw[qg] >> (mbit + quad * 4));
            uint32_t sh1 = (uint32_t)(mw[qg] >> (mbit + 16 + quad * 4));
            union { uint32_t d[4]; bf16x8 v; } sc;
            sc.d[0] = pkmask(sA[0], sA[1], sh0);
            sc.d[1] = pkmask(sA[2], sA[3], sh0 >> 2);
            sc.d[2] = pkmask(sB[0], sB[1], sh1);
            sc.d[3] = pkmask(sB[2], sB[3], sh1 >> 2);
            scf[qg] = sc.v;
        }

        // Phase 2: O += Sc.V over this 32-k slice (V straight from global)
#pragma unroll
        for (int di = 0; di < 4; ++di) {
            union { uint32_t d[4]; bf16x8 v; } vb;
            const uint32_t* vlo =
                (const uint32_t*)(vbase + (size_t)(di * 16 + l16) * SS + ks0 + quad * 4);
            const uint32_t* vhi =
                (const uint32_t*)(vbase + (size_t)(di * 16 + l16) * SS + ks0 + 16 + quad * 4);
            vb.d[0] = vlo[0]; vb.d[1] = vlo[1];
            vb.d[2] = vhi[0]; vb.d[3] = vhi[1];
#pragma unroll
            for (int qg = 0; qg < 4; ++qg)
                oacc[qg][di] = __builtin_amdgcn_mfma_f32_16x16x32_bf16(
                    scf[qg], vb.v, oacc[qg][di], 0, 0, 0);
        }
    }

    // Cross-wave reduction: wave w posts oacc[qg] (qg != w) into slot
    // (qg, writer-rank); wave w then sums its own qg == w. Stride 20 dwords
    // per lane: 16B-aligned, conflict-free b128.
#pragma unroll
    for (int qg = 0; qg < 4; ++qg) {
        if (qg != w) {
            int s = qg * 3 + w - (w > qg ? 1 : 0);
#pragma unroll
            for (int di = 0; di < 4; ++di)
                *(f32x4*)&Rs[s * 1280 + lane * 20 + di * 4] = oacc[qg][di];
        }
    }
    __syncthreads();
#pragma unroll
    for (int t = 0; t < 3; ++t) {
        int s = w * 3 + t;
#pragma unroll
        for (int di = 0; di < 4; ++di)
            oacc[w][di] += *(const f32x4*)&Rs[s * 1280 + lane * 20 + di * 4];
    }

    // Write merged-head O rows q = q0 + w*16 + quad*4 + r
#pragma unroll
    for (int di = 0; di < 4; ++di) {
        int d = di * 16 + l16;
#pragma unroll
        for (int r = 0; r < 4; ++r) {
            int qg_ = q0 + w * 16 + quad * 4 + r;
            O[((size_t)b * SS + qg_) * SE + h * SD + d] = f2bf(oacc[w][di][r]);
        }
    }
}

// ---------------------------------------------------------------------------
extern "C" void kernel_launch(void* const* d_in, const int* in_sizes, int n_in,
                              void* d_out, int out_size, void* d_ws,
                              size_t ws_size, hipStream_t stream) {
    const float* query = (const float*)d_in[0];
    const float* key   = (const float*)d_in[1];
    const float* value = (const float*)d_in[2];
    const int*   mask  = (const int*)d_in[3];
    float* out = (float*)d_out;

    // Buffer plan (zero d_ws; harness restores inputs before every launch):
    //  d_out [0,1M):  packed mask MpT (dead before O-proj writes d_out)
    //  mask buffer d_in[3] (33.5 MB) -> bf16 scratch after pack:
    //    [0,8M) qbf | [8,16) kbf | [16,24) vbf | [24,32) Wq|Wk|Wv|Wo
    //  d_in[0]: Qb [0,8M) | Om [8M,16M);  d_in[1]: Kb;  d_in[2]: Vtb
    const size_t NEL = (size_t)SB * SS * SE;  // 4,194,304
    unsigned long long* Mp = (unsigned long long*)d_out;
    short* mb   = (short*)d_in[3];
    short* qbf  = mb;
    short* kbf  = mb + NEL;
    short* vbf  = mb + 2 * NEL;
    short* Wqb  = mb + 3 * NEL;
    short* Wkb  = Wqb + SE * SE;
    short* Wvb  = Wkb + SE * SE;
    short* Wob  = Wvb + SE * SE;
    short* Qb   = (short*)d_in[0];
    short* Om   = (short*)d_in[0] + NEL;
    short* Kb   = (short*)d_in[1];
    short* Vtb  = (short*)d_in[2];

    dim3 tblk(256);

    // 1) pack mask (transposed bit layout) -> d_out  [must precede cvt!]
    pack_mask<<<dim3(2048), tblk, 0, stream>>>(mask, Mp);

    // 2) fp32 -> bf16 for q,k,v,W* into the dead mask buffer
    CvtArgs ca;
    ca.src[0] = query; ca.dst[0] = qbf;
    ca.src[1] = key;   ca.dst[1] = kbf;
    ca.src[2] = value; ca.dst[2] = vbf;
    ca.src[3] = (const float*)d_in[4];  ca.dst[3] = Wqb;
    ca.src[4] = (const float*)d_in[6];  ca.dst[4] = Wkb;
    ca.src[5] = (const float*)d_in[8];  ca.dst[5] = Wvb;
    ca.src[6] = (const float*)d_in[10]; ca.dst[6] = Wob;
    cvt_bf16<<<dim3(2048), tblk, 0, stream>>>(ca);

    // 3) fused Q,K,Vt projections (1/8 folded into Q; Vt = Wv.value^T swapped)
    GemmJob jq{qbf, Wqb, (const float*)d_in[5], Qb,  1, 0.125f};
    GemmJob jk{kbf, Wkb, (const float*)d_in[7], Kb,  1, 1.0f};
    GemmJob jv{Wvb, vbf, (const float*)d_in[9], Vtb, 3, 1.0f};
    gemm64<false><<<dim3(8, 64, 3), tblk, 0, stream>>>(jq, jk, jv);

    // 4) attention (register-resident scores, k-split waves, no loop LDS)
    attn4<<<dim3(SS / 64, SB * SH), tblk, 0, stream>>>(Qb, Kb, Vtb, Mp, Om);

    // 5) output projection (fp32 out; overwrites Mp region - dead)
    GemmJob jo{Om, Wob, (const float*)d_in[11], out, 0, 1.0f};
    gemm64<true><<<dim3(8, 64, 1), tblk, 0, stream>>>(jo, jo, jo);
}